// Round 11
// baseline (182.364 us; speedup 1.0000x reference)
//
#include <hip/hip_runtime.h>

#define N_ 4
#define C_ 64
#define H_ 224
#define W_ 224
#define HW_ (H_ * W_)        /* 50176 */
#define CHW_ (C_ * HW_)      /* 3211264 */
#define TOT_ (N_ * CHW_)     /* 12845056 */

typedef __bf16 bf8 __attribute__((ext_vector_type(8)));
typedef float  f4v __attribute__((ext_vector_type(4)));
typedef unsigned short u16;

__device__ __forceinline__ float relu_(float v) { return fmaxf(v, 0.f); }
__device__ __forceinline__ u16 f2bf(float f) {
    unsigned u = __builtin_bit_cast(unsigned, f);
    return (u16)((u + 0x7FFFu + ((u >> 16) & 1u)) >> 16);
}
__device__ __forceinline__ float bf2f(u16 h) {
    unsigned u = ((unsigned)h) << 16;
    return __builtin_bit_cast(float, u);
}

// async 16B global->LDS (LDS dest = wave-uniform base + lane*16)
__device__ __forceinline__ void gl_lds16(const void* g, void* l) {
    __builtin_amdgcn_global_load_lds(
        (const __attribute__((address_space(1))) void*)g,
        (__attribute__((address_space(3))) void*)l, 16, 0, 0);
}

// Wpre[sel][tap][o][k] bf16 <- wd[o][k][tap]   (B-operand ready: o rows, k contiguous)
__global__ __launch_bounds__(256) void prep_w(
    const float* __restrict__ wd1, const float* __restrict__ wd2,
    u16* __restrict__ wpre)
{
    int i = blockIdx.x * 256 + threadIdx.x;
    if (i >= 73728) return;
    int sel = i >= 36864;
    int r   = i - sel * 36864;
    int tap = r >> 12;
    int r2  = r & 4095;
    int o   = r2 >> 6, k = r2 & 63;
    const float* ws = sel ? wd2 : wd1;
    wpre[i] = f2bf(ws[o * 576 + k * 9 + tap]);
}

// T pass: block = 32-px row strip x 64 ch; thread = 4 px x 2 ch.
// NORM=false: in = x fp32 NCHW, T = dw(x)+x.
// NORM=true:  in = o1 fp32 NCHW, n1 = relu(bn1(o1)) on load (SS from raw sums),
//             T = dw(n1)+n1. OOB padding stays zero (norm applied in-image only).
// Wide float4 row loads, u32-packed LDS transpose, full-line NHWC bf16 writes.
// 1D grid with bijective XCD chunk swizzle (6272 = 8 x 784).
template<bool NORM>
__global__ __launch_bounds__(256) void tpass(
    const float* __restrict__ in, const float* __restrict__ wsh,
    const float* __restrict__ raw, const float* __restrict__ gamma,
    const float* __restrict__ beta, u16* __restrict__ th)
{
    __shared__ unsigned TL[32][36];   // [px][ch-pair], stride 36 words
    __shared__ float SS[128];

    const int tid = threadIdx.x;
    if (NORM) {
        if (tid < 64) {
            const float cnt = (float)(N_ * HW_);
            float mean = raw[tid] / cnt;
            float var  = raw[64 + tid] / cnt - mean * mean;
            float inv  = rsqrtf(var + 1e-5f);
            float scv  = gamma[tid] * inv;
            SS[tid]      = scv;
            SS[64 + tid] = fmaf(-scv, mean, beta[tid]);
        }
        __syncthreads();
    }

    float wk[9];
#pragma unroll
    for (int k = 0; k < 9; ++k) wk[k] = wsh[k];
    const float wc1 = wk[4] + 1.f;

    const int orig = blockIdx.x;                  // nwg = 6272 = 8*784
    const int swz  = (orig & 7) * 784 + (orig >> 3);
    const int n    = swz / 1568;
    const int rem  = swz - n * 1568;
    const int row  = rem / 7;
    const int strip = rem - row * 7;

    const int qd = tid & 7;          // pixel quad within strip
    const int c2 = tid >> 3;         // channel pair 0..31
    const int w0 = strip * 32 + qd * 4;
    const bool ym = row > 0, yp = row < H_ - 1;
    const bool xm = w0 > 0, xp = w0 + 4 < W_;

    float tq[2][4];
#pragma unroll
    for (int s = 0; s < 2; ++s) {
        const int ch = c2 * 2 + s;
        float sc = 1.f, sh = 0.f;
        if (NORM) { sc = SS[ch]; sh = SS[64 + ch]; }
        auto nrm = [&](float v) { return NORM ? relu_(fmaf(sc, v, sh)) : v; };
        const float* bp = in + (size_t)n * CHW_ + (size_t)ch * HW_ + row * W_ + w0;

        float m0[4] = {0,0,0,0}, m1[4], m2[4] = {0,0,0,0};
        float l0 = 0.f, r0 = 0.f, l1 = 0.f, r1 = 0.f, l2 = 0.f, r2 = 0.f;
        if (ym) {
            float4 v = *(const float4*)(bp - W_);
            m0[0] = nrm(v.x); m0[1] = nrm(v.y); m0[2] = nrm(v.z); m0[3] = nrm(v.w);
            if (xm) l0 = nrm(bp[-W_ - 1]);
            if (xp) r0 = nrm(bp[-W_ + 4]);
        }
        {
            float4 v = *(const float4*)bp;
            m1[0] = nrm(v.x); m1[1] = nrm(v.y); m1[2] = nrm(v.z); m1[3] = nrm(v.w);
            if (xm) l1 = nrm(bp[-1]);
            if (xp) r1 = nrm(bp[4]);
        }
        if (yp) {
            float4 v = *(const float4*)(bp + W_);
            m2[0] = nrm(v.x); m2[1] = nrm(v.y); m2[2] = nrm(v.z); m2[3] = nrm(v.w);
            if (xm) l2 = nrm(bp[W_ - 1]);
            if (xp) r2 = nrm(bp[W_ + 4]);
        }
#pragma unroll
        for (int j = 0; j < 4; ++j) {
            float a0 = (j == 0) ? l0 : m0[j - 1];
            float a2 = (j == 3) ? r0 : m0[j + 1];
            float b0 = (j == 0) ? l1 : m1[j - 1];
            float b2 = (j == 3) ? r1 : m1[j + 1];
            float c0 = (j == 0) ? l2 : m2[j - 1];
            float c2v = (j == 3) ? r2 : m2[j + 1];
            float t = wc1 * m1[j];
            t = fmaf(wk[0], a0,    t);
            t = fmaf(wk[1], m0[j], t);
            t = fmaf(wk[2], a2,    t);
            t = fmaf(wk[3], b0,    t);
            t = fmaf(wk[5], b2,    t);
            t = fmaf(wk[6], c0,    t);
            t = fmaf(wk[7], m2[j], t);
            t = fmaf(wk[8], c2v,   t);
            tq[s][j] = t;
        }
    }
#pragma unroll
    for (int j = 0; j < 4; ++j)
        TL[qd * 4 + j][c2] = (unsigned)f2bf(tq[0][j]) | ((unsigned)f2bf(tq[1][j]) << 16);
    __syncthreads();

    const int px = tid >> 3, s = tid & 7;
    uint4 v = *(const uint4*)&TL[px][s * 4];
    *(uint4*)(th + (size_t)(n * HW_ + row * W_ + strip * 32 + px) * 64 + s * 8) = v;
}

// Dense 3x3 conv as implicit GEMM over NHWC bf16 T (R10-proven body).
// Both layers store fp32 NCHW float4 (coalesced).
// LAYER 1: resid = x;             dst = o1 (d_out).
// LAYER 2: resid = relu(bn1(o1)); dst = o2 in-place on d_out (same-thread RMW).
template<int LAYER>
__global__ __launch_bounds__(256, 3) void conv_mfma(
    const u16* __restrict__ th, const u16* __restrict__ wpre,
    const float* __restrict__ bd,
    const float* __restrict__ rawin, const float* __restrict__ gamma,
    const float* __restrict__ beta,
    const float* resx,              // may alias dstf (LAYER 2)
    const u16* __restrict__ zp,
    float* dstf,
    float* __restrict__ raw)
{
    __shared__ __align__(16) char TlB[340 * 128];   // 43520 B
    __shared__ float Sr[128];
    __shared__ float SS[128];

    const int tid = threadIdx.x;
    // XCD band swizzle: 784 = 8 * 98; XCD k owns a contiguous 112-row band
    // of image n=k/2 (matches tpass banding for cross-kernel L2 reuse).
    const int orig = blockIdx.x;
    const int swz  = (orig & 7) * 98 + (orig >> 3);
    const int wx   = swz % 7;
    const int t_   = swz / 7;            // n*28 + hy
    const int n    = t_ / 28;
    const int hy   = t_ - n * 28;
    const int h0 = hy * 8, w0 = wx * 32;

    const int lane = tid & 63, wg = tid >> 6;
    const int l15 = lane & 15, lg = lane >> 4;
    const int o = wg * 16 + l15;

    if (LAYER == 2 && tid < 64) {
        const float cnt = (float)(N_ * HW_);
        float mean = rawin[tid] / cnt;
        float var  = rawin[64 + tid] / cnt - mean * mean;
        float inv  = rsqrtf(var + 1e-5f);
        float scv  = gamma[tid] * inv;
        SS[tid]      = scv;
        SS[64 + tid] = fmaf(-scv, mean, beta[tid]);
    }

    // B fragments: [tap][cc] -> 18 x bf16x8 in registers (L2-cached source)
    bf8 B[18];
#pragma unroll
    for (int tap = 0; tap < 9; ++tap)
#pragma unroll
        for (int cc = 0; cc < 2; ++cc)
            B[tap * 2 + cc] = *(const bf8*)(wpre + ((tap * 64 + o) * 64 + cc * 32 + lg * 8));

    // Stage T halo (34x10 pixels x 128B) via global_load_lds:
    // LDS dest linear (wave base + lane*16); XOR swizzle applied to the
    // GLOBAL source address (involution; read side unchanged). OOB -> zero page.
#pragma unroll
    for (int it = 0; it < 11; ++it) {
        const int f = it * 256 + tid;
        if (f < 2720) {
            const int pix = f >> 3, s = f & 7;
            const int hr = pix / 34, wc = pix - hr * 34;
            const int gh = h0 - 1 + hr, gw = w0 - 1 + wc;
            const u16* src = zp;
            if ((unsigned)gh < (unsigned)H_ && (unsigned)gw < (unsigned)W_)
                src = th + (size_t)(n * HW_ + gh * W_ + gw) * 64 +
                      ((s * 8) ^ ((pix & 7) << 3));
            gl_lds16(src, TlB + (size_t)(it * 256 + (tid & 192)) * 16);
        }
    }
    __syncthreads();

    f4v acc[16];
#pragma unroll
    for (int mf = 0; mf < 16; ++mf) acc[mf] = (f4v){0.f, 0.f, 0.f, 0.f};

#pragma unroll
    for (int mf = 0; mf < 16; ++mf) {
        const int h = mf >> 1, half = mf & 1;
#pragma unroll
        for (int tap = 0; tap < 9; ++tap) {
            const int dr = tap / 3, dc = tap - dr * 3;
            const int hp = (h + dr) * 34 + half * 16 + dc + l15;
#pragma unroll
            for (int cc = 0; cc < 2; ++cc) {
                const bf8 A = *(const bf8*)(TlB + hp * 128 +
                                            ((cc * 64 + lg * 16) ^ ((hp & 7) << 4)));
                acc[mf] = __builtin_amdgcn_mfma_f32_16x16x32_bf16(
                    A, B[tap * 2 + cc], acc[mf], 0, 0, 0);
            }
        }
    }

    // Epilogue: bias + residual + coalesced float4 store + per-channel stats
    const float bv = bd[o];
    float scO = 1.f, shO = 0.f;
    if (LAYER == 2) { scO = SS[o]; shO = SS[64 + o]; }
    float ps1 = 0.f, ps2 = 0.f;
#pragma unroll
    for (int mf = 0; mf < 16; ++mf) {
        const int h = h0 + (mf >> 1);
        const int w = w0 + (mf & 1) * 16 + lg * 4;
        const size_t cidx = (size_t)n * CHW_ + (size_t)o * HW_ + h * W_ + w;
        float4 rx = *(const float4*)(resx + cidx);
        if (LAYER == 2) {
            rx.x = relu_(fmaf(scO, rx.x, shO));
            rx.y = relu_(fmaf(scO, rx.y, shO));
            rx.z = relu_(fmaf(scO, rx.z, shO));
            rx.w = relu_(fmaf(scO, rx.w, shO));
        }
        float4 st;
        st.x = acc[mf][0] + bv + rx.x;
        st.y = acc[mf][1] + bv + rx.y;
        st.z = acc[mf][2] + bv + rx.z;
        st.w = acc[mf][3] + bv + rx.w;
        *(float4*)(dstf + cidx) = st;
        ps1 += (st.x + st.y) + (st.z + st.w);
        ps2 += fmaf(st.x, st.x, fmaf(st.y, st.y, fmaf(st.z, st.z, st.w * st.w)));
    }
    ps1 += __shfl_xor(ps1, 16); ps1 += __shfl_xor(ps1, 32);
    ps2 += __shfl_xor(ps2, 16); ps2 += __shfl_xor(ps2, 32);
    if (lane < 16) { Sr[o] = ps1; Sr[64 + o] = ps2; }
    __syncthreads();
    if (tid < 128) atomicAdd(&raw[tid], Sr[tid]);
}

// io = relu(bn2(io)) + x, bn2 scale/shift computed in-block from raw2 sums.
__global__ __launch_bounds__(256) void final_k(
    float4* io, const float* __restrict__ raw, const float* __restrict__ gamma,
    const float* __restrict__ beta, const float4* __restrict__ x)
{
    __shared__ float SS[128];
    if (threadIdx.x < 64) {
        const int c = threadIdx.x;
        const float cnt = (float)(N_ * HW_);
        float mean = raw[c] / cnt;
        float var  = raw[64 + c] / cnt - mean * mean;
        float inv  = rsqrtf(var + 1e-5f);
        float scv  = gamma[c] * inv;
        SS[c]      = scv;
        SS[64 + c] = fmaf(-scv, mean, beta[c]);
    }
    __syncthreads();

    const int nq = TOT_ / 4;
    for (int i = blockIdx.x * 256 + threadIdx.x; i < nq; i += gridDim.x * 256) {
        int c = (i / (HW_ / 4)) & 63;
        float sc = SS[c], sh = SS[64 + c];
        float4 v = io[i], xx = x[i];
        float4 rr;
        rr.x = relu_(fmaf(sc, v.x, sh)) + xx.x;
        rr.y = relu_(fmaf(sc, v.y, sh)) + xx.y;
        rr.z = relu_(fmaf(sc, v.z, sh)) + xx.z;
        rr.w = relu_(fmaf(sc, v.w, sh)) + xx.w;
        io[i] = rr;
    }
}

extern "C" void kernel_launch(void* const* d_in, const int* in_sizes, int n_in,
                              void* d_out, int out_size, void* d_ws, size_t ws_size,
                              hipStream_t stream)
{
    const float* x    = (const float*)d_in[0];
    const float* wsh1 = (const float*)d_in[1];
    const float* wd1  = (const float*)d_in[2];
    const float* bd1  = (const float*)d_in[3];
    const float* wsh2 = (const float*)d_in[4];
    const float* wd2  = (const float*)d_in[5];
    const float* bd2  = (const float*)d_in[6];
    const float* g1   = (const float*)d_in[7];
    const float* be1  = (const float*)d_in[8];
    const float* g2   = (const float*)d_in[9];
    const float* be2  = (const float*)d_in[10];

    float* out = (float*)d_out;
    u16* Th   = (u16*)d_ws;                // TOT_ u16  (T tensor NHWC, both layers)
    u16* Wpre = Th + TOT_;                 // 73728 u16
    float* raw1 = (float*)(Wpre + 73728);  // 128
    float* raw2 = raw1 + 128;              // 128
    u16*   zp   = (u16*)(raw2 + 128);      // 64 u16 zero page (OOB halo src)

    // zero raw1+raw2+zp in one async memset (graph-capture safe)
    hipMemsetAsync(raw1, 0, 256 * sizeof(float) + 128, stream);
    prep_w<<<288, 256, 0, stream>>>(wd1, wd2, Wpre);

    const int tgrid = N_ * H_ * 7;     // 6272 = 8 * 784 (swizzle-divisible)
    const int cgrid = 784;             // 8 * 98, 1D XCD-banded

    // T1 = dw(x) + x  (NHWC bf16, fused transpose from fp32 NCHW)
    tpass<false><<<tgrid, 256, 0, stream>>>(x, wsh1, nullptr, nullptr, nullptr, Th);
    // o1 = conv(T1) + b1 + x -> d_out (fp32 NCHW, coalesced); raw1 stats
    conv_mfma<1><<<cgrid, 256, 0, stream>>>(Th, Wpre, bd1,
                                            nullptr, nullptr, nullptr,
                                            x, zp, out, raw1);
    // T2 = dw(n1) + n1, n1 = relu(bn1(o1)) on load; bn1 stats folded in
    tpass<true><<<tgrid, 256, 0, stream>>>(out, wsh2, raw1, g1, be1, Th);
    // o2 = conv(T2) + b2 + n1 -> d_out in-place (same-thread RMW); raw2 stats
    conv_mfma<2><<<cgrid, 256, 0, stream>>>(Th, Wpre + 36864, bd2,
                                            raw1, g1, be1,
                                            out, zp, out, raw2);
    // out = relu(bn2(o2)) + x; bn2 stats folded in
    final_k<<<2048, 256, 0, stream>>>((float4*)out, raw2, g2, be2, (const float4*)x);
}